// Round 2
// baseline (234.948 us; speedup 1.0000x reference)
//
#include <hip/hip_runtime.h>
#include <hip/hip_bf16.h>
#include <hip/hip_fp16.h>
#include <math.h>

// Problem constants (from reference)
#define B_   64
#define L_   512
#define V_   20000
#define P_   150
#define M_   6
#define KDIM 300
#define NOUT 750          // P_ * (M_-1) used transition scores
#define CWS  752          // padded row stride (16B-aligned float4 rows)
#define NEGF (-1.0e9f)

// f32 fallback GEMM tiling
#define BM 128
#define BN 128
#define BK 16
#define LDP 132

// MFMA path constants
#define KP 320            // K padded: 10 tiles of 32
#define NIT 10            // K-iters
#define NVG 157           // v-groups of 128
#define NJ  6             // n-groups of 128
#define TILE_U4 1024      // uint4 per (group,it) tile: [s 2][q 4][row 128]
#define SA 1024.0f        // emb scale (keeps lo-split out of fp16 subnormals)
#define SB 16384.0f       // diags scale
#define INV24 (5.9604644775390625e-8f)   // 2^-24

// Scan chunking
#define TCHUNK 32
#define NCHUNK (L_ / TCHUNK)   // 16
#define WARM   5
#define CS_STRIDE 160
#define KVBUF 3           // k2 pipeline depth-2 -> 3 LDS buffers

typedef _Float16 f16x8 __attribute__((ext_vector_type(8)));
typedef float f32x16 __attribute__((ext_vector_type(16)));

__device__ __forceinline__ float logsigf(float x) {
    // matches jax: -softplus(-x) = min(x,0) - log1p(exp(-|x|))
    return fminf(x, 0.f) - log1pf(expf(-fabsf(x)));
}

// fast variant for k1m epilogue: v_exp_f32/v_log_f32, abs err ~6e-8 (flip-safe budget)
__device__ __forceinline__ float logsigf_fast(float x) {
    return fminf(x, 0.f) - __logf(1.f + __expf(-fabsf(x)));
}

// async global->LDS, 16 B per lane; LDS dst = wave-uniform base + lane*16
__device__ __forceinline__ void gload_lds16(const void* gp, void* lp) {
    __builtin_amdgcn_global_load_lds(
        (const __attribute__((address_space(1))) unsigned int*)gp,
        (__attribute__((address_space(3))) unsigned int*)lp, 16, 0, 0);
}

// ---------------- MFMA path ----------------

// P12 (fused p1+p2, one launch):
// blocks [0, NVG*5): emb [300][20000] -> fp16 hi/lo splits, DMA-tiled
//   a_t[g 157][it 10][s 2][q 4][row 128] uint4.
// blocks [NVG*5, NVG*5+60): diags (dpm-mapped, scaled) -> b_t[j 6][it 10][s2][q4][row128].
__global__ __launch_bounds__(256) void p12_split(
    const float* __restrict__ emb, const float* __restrict__ diags,
    uint4* __restrict__ a_t, uint4* __restrict__ b_t)
{
    __shared__ float T[64][132];
    const int t   = threadIdx.x;
    const int bid = blockIdx.x;

    if (bid < NVG * 5) {
        // ---- p1 part ----
        const int gx = bid % NVG;
        const int ky = bid / NVG;            // 0..4
        const int v0 = gx * 128;
        const int k0 = ky * 64;

        #pragma unroll
        for (int pass = 0; pass < 8; ++pass) {
            int flat = pass * 256 + t;
            int krow = flat >> 5;
            int c4   = (flat & 31) * 4;
            int kg   = k0 + krow;
            int v    = v0 + c4;
            float4 f = {0.f, 0.f, 0.f, 0.f};
            if (kg < KDIM && v + 3 < V_)
                f = *(const float4*)(emb + (size_t)kg * V_ + v);
            *(float4*)&T[krow][c4] = f;
        }
        __syncthreads();

        const int vv = t >> 1;
        const int kh = (t & 1) * 32;
        const int it = ky * 2 + (kh >> 5);
        const int v  = v0 + vv;
        if (v < V_) {
            union { ushort u[8]; uint4 q; } H[4], Lo[4];
            #pragma unroll
            for (int i = 0; i < 32; ++i) {
                float x = T[kh + i][vv] * SA;
                __half h = __float2half_rn(x);
                float rem = x - __half2float(h);
                H[i >> 3].u[i & 7]  = __half_as_ushort(h);
                Lo[i >> 3].u[i & 7] = __half_as_ushort(__float2half_rn(rem));
            }
            uint4* tile = a_t + ((size_t)gx * NIT + it) * TILE_U4;
            #pragma unroll
            for (int c = 0; c < 4; ++c) {
                tile[      c * 128 + vv] = H[c].q;
                tile[512 + c * 128 + vv] = Lo[c].q;
            }
        }
    } else {
        // ---- p2 part ----
        const int bidx = bid - NVG * 5;      // j*10 + it, 0..59
        const int it   = bidx % NIT;
        const int j    = bidx / NIT;
        const int row  = t >> 1;
        const int qh   = (t & 1) * 2;
        const int n    = j * 128 + row;
        const bool nok = (n < NOUT);
        const int pm   = nok ? ((n / 5) * 6 + (n % 5)) : 0;
        uint4* tile = b_t + (size_t)bidx * TILE_U4;
        #pragma unroll
        for (int qq = 0; qq < 2; ++qq) {
            int q = qh + qq;
            union { ushort u[8]; uint4 v; } H, Lo;
            #pragma unroll
            for (int e = 0; e < 8; ++e) {
                int k = it * 32 + q * 8 + e;
                float x = (nok && k < KDIM) ? diags[(size_t)pm * KDIM + k] * SB : 0.f;
                __half h = __float2half_rn(x);
                float rem = x - __half2float(h);
                H.u[e]  = __half_as_ushort(h);
                Lo.u[e] = __half_as_ushort(__float2half_rn(rem));
            }
            tile[      q * 128 + row] = H.v;
            tile[512 + q * 128 + row] = Lo.v;
        }
    }
}

// K1 (MFMA, round-3 rework): C = a1@b1 + a1@b2 + a2@b1 (fp16 split-f32).
//
// Round-2 post-mortem: gload_lds staging from L3 runs at ~10 B/cyc/CU
// (queue-depth-limited DMA x ~700cy L3 latency); 6.5k cyc per CU-iter for
// 64 KB staged == the whole 50 us. NT stores / L2-reuse theory refuted
// (FETCH_SIZE only 16.6 MB).
//
// New structure:
//  - Tile 128 v-rows x 384 n-cols per block (2 n-halves per g): a_t re-read
//    6x -> 2x (154 -> 51 MB of L3 read), blocks 960 -> 314.
//  - 512 threads, 8 waves in 2(row) x 4(col) grid; acc = 2x3 f32x16 (96 VGPR).
//  - REGISTER staging (plain global_load_dwordx4 -> ds_write_b128), NOT
//    gload_lds: in-flight bytes scale with waves (8 KB/wave -> 64 KB/CU),
//    so L3 latency is covered. Loads for iter it+2 issue at the TOP of
//    iter it -> a full compute phase (~2k cyc) before __syncthreads'
//    vmcnt(0) drain -> drain is nearly free. No fragile asm waitcnts.
//  - LDS: 2 x 64 KB stage buffers (A 16 KB + B 48 KB per k-iter), 1 blk/CU.
// Accumulation order per output element is identical -> bitwise-same C.
__global__ __launch_bounds__(512, 2) void k1m_gemm(
    const uint4* __restrict__ a_t, const uint4* __restrict__ b_t,
    const float* __restrict__ bias, const float* __restrict__ wildc,
    float* __restrict__ cw)
{
    const int bid = blockIdx.x;              // 0..313
    const int g   = bid >> 1;                // v-group 0..156
    const int h   = bid & 1;                 // n-half (384 cols each)

    __shared__ uint4 sm[2][4096];            // 2 x 64 KB
    const int t    = threadIdx.x;            // 0..511
    const int lane = t & 63;
    const int w    = t >> 6;                 // wave 0..7
    const int wr   = w >> 2;                 // row-half (64 rows)
    const int wc   = w & 3;                  // col-quarter (96 cols)
    const int v0   = g * 128;

    const int fk16 = lane >> 5;
    const int fm   = lane & 31;

    const uint4* abase = a_t + (size_t)g * NIT * TILE_U4;
    const uint4* bbase[3];
    #pragma unroll
    for (int jj = 0; jj < 3; ++jj)
        bbase[jj] = b_t + (size_t)(h * 3 + jj) * NIT * TILE_U4;

    f32x16 acc[2][3];
    #pragma unroll
    for (int i = 0; i < 2; ++i)
        #pragma unroll
        for (int jj = 0; jj < 3; ++jj)
            #pragma unroll
            for (int r = 0; r < 16; ++r) acc[i][jj][r] = 0.f;

    uint4 ra[8], rb[8];                      // staging sets: even its -> ra, odd -> rb

    // load set for iter it: 8 x 16 B per thread (A: 2, B: 6)
    #define LOAD_SET(R, IT)                                            \
        do {                                                           \
            const uint4* ab = abase + (size_t)(IT) * TILE_U4;          \
            R[0] = ab[t];                                              \
            R[1] = ab[512 + t];                                        \
            _Pragma("unroll")                                          \
            for (int jj = 0; jj < 3; ++jj) {                           \
                const uint4* bb = bbase[jj] + (size_t)(IT) * TILE_U4;  \
                R[2 + 2 * jj]     = bb[t];                             \
                R[2 + 2 * jj + 1] = bb[512 + t];                       \
            }                                                          \
        } while (0)

    // write set into stage buffer bsel (linear, conflict-free b128 writes)
    #define WRITE_SET(R, BSEL)                                         \
        do {                                                           \
            uint4* smb = &sm[(BSEL)][0];                               \
            smb[t]       = R[0];                                       \
            smb[512 + t] = R[1];                                       \
            _Pragma("unroll")                                          \
            for (int jj = 0; jj < 3; ++jj) {                           \
                smb[1024 + jj * 1024 + t]       = R[2 + 2 * jj];       \
                smb[1024 + jj * 1024 + 512 + t] = R[2 + 2 * jj + 1];   \
            }                                                          \
        } while (0)

    // prologue: stage it=0, issue it=1
    LOAD_SET(ra, 0);
    WRITE_SET(ra, 0);
    LOAD_SET(rb, 1);
    __syncthreads();

    #pragma unroll
    for (int it = 0; it < NIT; ++it) {
        // 1) issue loads for it+2 early (covered by this iter's compute)
        if (it + 2 < NIT) {
            if ((it & 1) == 0) { LOAD_SET(ra, it + 2); }
            else               { LOAD_SET(rb, it + 2); }
        }

        // 2) compute iter it from sm[it&1]
        const uint4* smc = &sm[it & 1][0];
        #pragma unroll
        for (int s = 0; s < 2; ++s) {
            const int q = s * 2 + fk16;
            f16x8 A1[2], A2[2], B1[3], B2[3];
            #pragma unroll
            for (int ri = 0; ri < 2; ++ri) {
                A1[ri] = *(const f16x8*)&smc[      q * 128 + wr * 64 + ri * 32 + fm];
                A2[ri] = *(const f16x8*)&smc[512 + q * 128 + wr * 64 + ri * 32 + fm];
            }
            #pragma unroll
            for (int cj = 0; cj < 3; ++cj) {
                const int nc  = wc * 96 + cj * 32;
                const int bofs = 1024 + (nc >> 7) * 1024 + q * 128 + (nc & 127) + fm;
                B1[cj] = *(const f16x8*)&smc[bofs];
                B2[cj] = *(const f16x8*)&smc[bofs + 512];
            }
            #pragma unroll
            for (int ri = 0; ri < 2; ++ri)
                #pragma unroll
                for (int cj = 0; cj < 3; ++cj) {
                    acc[ri][cj] = __builtin_amdgcn_mfma_f32_32x32x16_f16(A1[ri], B1[cj], acc[ri][cj], 0, 0, 0);
                    acc[ri][cj] = __builtin_amdgcn_mfma_f32_32x32x16_f16(A1[ri], B2[cj], acc[ri][cj], 0, 0, 0);
                    acc[ri][cj] = __builtin_amdgcn_mfma_f32_32x32x16_f16(A2[ri], B1[cj], acc[ri][cj], 0, 0, 0);
                }
        }

        // 3) stage it+1 into the other buffer (loads landed during prev iter)
        if (it + 1 < NIT) {
            if ((it & 1) == 0) { WRITE_SET(rb, (it + 1) & 1); }
            else               { WRITE_SET(ra, (it + 1) & 1); }
            __syncthreads();
        }
    }
    #undef LOAD_SET
    #undef WRITE_SET

    // epilogue: C/D layout col=lane&31, row=(r&3)+8*(r>>2)+4*(lane>>5)
    float biasv[3], lwv[3]; int ncol[3]; bool nok[3];
    #pragma unroll
    for (int cj = 0; cj < 3; ++cj) {
        int n = h * 384 + wc * 96 + cj * 32 + fm;
        ncol[cj] = n;
        nok[cj]  = (n < NOUT);
        int nc = nok[cj] ? n : 0;
        int pm = (nc / 5) * 6 + (nc % 5);
        biasv[cj] = bias[pm];
        lwv[cj]   = logsigf_fast(wildc[nc]);
    }
    #pragma unroll
    for (int ri = 0; ri < 2; ++ri) {
        int vbase = v0 + wr * 64 + ri * 32 + 4 * fk16;
        #pragma unroll
        for (int cj = 0; cj < 3; ++cj) {
            if (!nok[cj]) continue;
            #pragma unroll
            for (int r = 0; r < 16; ++r) {
                int v = vbase + (r & 3) + 8 * (r >> 2);
                if (v < V_) {
                    float val = acc[ri][cj][r] * INV24 + biasv[cj];
                    __builtin_nontemporal_store(
                        fmaxf(logsigf_fast(val), lwv[cj]),
                        &cw[(size_t)v * CWS + ncol[cj]]);
                }
            }
        }
    }
}

// ---------------- f32 fallback (round-2 kernel) ----------------

__global__ __launch_bounds__(256) void k1_gemm_cw(
    const float* __restrict__ emb,
    const float* __restrict__ diags,
    const float* __restrict__ bias,
    const float* __restrict__ wildc,
    float* __restrict__ cw)
{
    __shared__ float As[BK][LDP];
    __shared__ float Bs[BK][LDP];

    const int tid = threadIdx.x;
    const int v0 = blockIdx.x * BM;
    const int n0 = blockIdx.y * BN;
    const int tx = tid & 15;
    const int ty = tid >> 4;

    float acc[8][8];
    #pragma unroll
    for (int i = 0; i < 8; ++i)
        #pragma unroll
        for (int j = 0; j < 8; ++j) acc[i][j] = 0.f;

    const int a_k = tid >> 4;
    const int a_v = (tid & 15) * 8;
    const int b_n   = tid >> 1;
    const int b_kof = (tid & 1) * 8;

    int  brow;
    bool bval;
    {
        int n = n0 + b_n;
        bval = (n < NOUT);
        brow = bval ? ((n / 5) * 6 + (n % 5)) : 0;
    }

    for (int k0 = 0; k0 < KDIM; k0 += BK) {
        {
            float4 f0 = {0,0,0,0}, f1 = {0,0,0,0};
            int k = k0 + a_k;
            if (k < KDIM) {
                const float* src = emb + (size_t)k * V_ + v0 + a_v;
                if (v0 + a_v + 3 < V_) f0 = *(const float4*)src;
                if (v0 + a_v + 7 < V_) f1 = *(const float4*)(src + 4);
            }
            *(float4*)&As[a_k][a_v]     = f0;
            *(float4*)&As[a_k][a_v + 4] = f1;
        }
        {
            float4 f = {0,0,0,0}, g = {0,0,0,0};
            if (bval) {
                const float* src = diags + (size_t)brow * KDIM + k0 + b_kof;
                if (k0 + b_kof + 3 < KDIM) f = *(const float4*)src;
                if (k0 + b_kof + 7 < KDIM) g = *(const float4*)(src + 4);
            }
            Bs[b_kof + 0][b_n] = f.x;
            Bs[b_kof + 1][b_n] = f.y;
            Bs[b_kof + 2][b_n] = f.z;
            Bs[b_kof + 3][b_n] = f.w;
            Bs[b_kof + 4][b_n] = g.x;
            Bs[b_kof + 5][b_n] = g.y;
            Bs[b_kof + 6][b_n] = g.z;
            Bs[b_kof + 7][b_n] = g.w;
        }
        __syncthreads();
        #pragma unroll
        for (int k = 0; k < BK; ++k) {
            float4 a0 = *(const float4*)&As[k][tx * 4];
            float4 a1 = *(const float4*)&As[k][64 + tx * 4];
            float4 b0 = *(const float4*)&Bs[k][ty * 8];
            float4 b1 = *(const float4*)&Bs[k][ty * 8 + 4];
            float av[8] = {a0.x, a0.y, a0.z, a0.w, a1.x, a1.y, a1.z, a1.w};
            float bv[8] = {b0.x, b0.y, b0.z, b0.w, b1.x, b1.y, b1.z, b1.w};
            #pragma unroll
            for (int i = 0; i < 8; ++i)
                #pragma unroll
                for (int j = 0; j < 8; ++j)
                    acc[i][j] = fmaf(av[i], bv[j], acc[i][j]);
        }
        __syncthreads();
    }

    float biasv[8], lwv[8];
    #pragma unroll
    for (int j = 0; j < 8; ++j) {
        int n  = n0 + ty * 8 + j;
        int nc = (n < NOUT) ? n : 0;
        int pm = (nc / 5) * 6 + (nc % 5);
        biasv[j] = bias[pm];
        lwv[j]   = logsigf(wildc[nc]);
    }
    #pragma unroll
    for (int i = 0; i < 8; ++i) {
        int v = v0 + ((i < 4) ? (tx * 4 + i) : (64 + tx * 4 + (i - 4)));
        if (v >= V_) continue;
        float r[8];
        #pragma unroll
        for (int j = 0; j < 8; ++j)
            r[j] = fmaxf(logsigf(acc[i][j] + biasv[j]), lwv[j]);
        float* dst = cw + (size_t)v * CWS + n0 + ty * 8;
        if (n0 + ty * 8     < NOUT) *(float4*)dst       = make_float4(r[0], r[1], r[2], r[3]);
        if (n0 + ty * 8 + 4 < NOUT) *(float4*)(dst + 4) = make_float4(r[4], r[5], r[6], r[7]);
    }
}

// ---------------- scan (pipelined LDS staging) + finalize ----------------

// 3-buffer, depth-2 pipeline with counted s_waitcnt vmcnt(3) + raw s_barrier
// (one barrier per round); see round-2 notes. Bit-identical values.
__global__ __launch_bounds__(192) void k2_scan(
    const int* __restrict__ docs,
    const int* __restrict__ doc_lens,
    const float* __restrict__ cw,
    float* __restrict__ cs)
{
    const int ci = blockIdx.x;
    const int b  = blockIdx.y;
    const int t0 = ci * TCHUNK;
    const int ts = (t0 >= WARM) ? (t0 - WARM) : 0;
    const int dl = doc_lens[b];
    const int te = min(t0 + TCHUNK, dl);
    const int nt = te - ts;              // tokens to process (may be <= 0)

    __shared__ int   toks[TCHUNK + WARM];
    __shared__ float rows[KVBUF][3][768];   // 27 KB: [buf][row-in-round][752 used]

    const int t    = threadIdx.x;
    const int lane = t & 63;
    const int w    = t >> 6;             // wave 0..2

    if (t < TCHUNK + WARM) {
        int tt = ts + t;
        toks[t] = docs[b * L_ + min(tt, L_ - 1)];
    }
    __syncthreads();                     // toks ready; drains all prior vmem

    const int p      = t;                // pattern if < P_
    const int e      = (p < 50) ? 3 : (p < 100) ? 4 : 5;
    const int warm_n = t0 - ts;
    float h1 = NEGF, h2 = NEGF, h3 = NEGF, h4 = NEGF, h5 = NEGF, sc = NEGF;

    const int nrounds = (nt > 0) ? (nt + 2) / 3 : 0;

    // prologue: issue DMA for rounds 0 and 1 (wave w stages row w of a round)
    for (int r0 = 0; r0 < 2; ++r0) {
        if (r0 >= nrounds) break;
        int idx = min(3 * r0 + w, nt - 1);
        const char* rowp = (const char*)(cw + (size_t)toks[idx] * CWS);
        char* lbase = (char*)&rows[r0][w][0];
        #pragma unroll
        for (int jj = 0; jj < 3; ++jj)
            gload_lds16(rowp + jj * 1024 + lane * 16,
                        lbase + jj * 1024 + lane * 16);
    }

    int bufc = 0;
    for (int r = 0; r < nrounds; ++r) {
        // drain THIS round's DMA only; keep round r+1's 3 loads in flight
        if (r + 1 < nrounds) {
            asm volatile("s_waitcnt vmcnt(3)" ::: "memory");
        } else {
            asm volatile("s_waitcnt vmcnt(0)" ::: "memory");
        }
        __builtin_amdgcn_s_barrier();
        asm volatile("" ::: "memory");   // fence: no rows-read hoists above barrier

        if (r + 2 < nrounds) {           // prefetch round r+2 (buffer of round r-1)
            int rn  = r + 2;
            int idx = min(3 * rn + w, nt - 1);
            const char* rowp = (const char*)(cw + (size_t)toks[idx] * CWS);
            int bn = bufc + 2; if (bn >= KVBUF) bn -= KVBUF;
            char* lbase = (char*)&rows[bn][w][0];
            #pragma unroll
            for (int jj = 0; jj < 3; ++jj)
                gload_lds16(rowp + jj * 1024 + lane * 16,
                            lbase + jj * 1024 + lane * 16);
        }

        #pragma unroll
        for (int u = 0; u < 3; ++u) {
            int i2 = 3 * r + u;
            if (i2 >= nt) break;
            if (p < P_) {
                const float* rp = &rows[bufc][u][p * 5];
                float c0 = rp[0], c1 = rp[1], c2 = rp[2], c3 = rp[3], c4 = rp[4];
                h5 = h4 + c4;
                h4 = h3 + c3;
                h3 = h2 + c2;
                h2 = h1 + c1;
                h1 = c0;                 // h0 = 0 always
                if (i2 >= warm_n) {
                    float esv = (e == 3) ? h3 : (e == 4) ? h4 : h5;
                    sc = fmaxf(sc, esv);
                }
            }
        }
        bufc = (bufc + 1 == KVBUF) ? 0 : bufc + 1;
        // no second barrier: the barrier at top of round r+1 orders
        // compute(r) (all waves) before DMA(r+3) overwrites buf[r%3]
    }
    if (p < P_) cs[(size_t)(b * NCHUNK + ci) * CS_STRIDE + p] = sc;
}

__device__ __forceinline__ float block_sum192(float v, volatile float* red, int tid) {
    #pragma unroll
    for (int off = 32; off > 0; off >>= 1) v += __shfl_down(v, off, 64);
    __syncthreads();
    if ((tid & 63) == 0) red[tid >> 6] = v;
    __syncthreads();
    return red[0] + red[1] + red[2];
}

__global__ __launch_bounds__(192) void k3_final(
    const float* __restrict__ cs,
    const float* __restrict__ gamma,
    const float* __restrict__ beta,
    const float* __restrict__ lw,
    const float* __restrict__ lb,
    float* __restrict__ out)
{
    __shared__ float red[3];
    const int b   = blockIdx.x;
    const int tid = threadIdx.x;
    float s = 0.f;
    if (tid < P_) {
        float m = NEGF;
        const float* row = cs + (size_t)b * NCHUNK * CS_STRIDE + tid;
        #pragma unroll
        for (int ci = 0; ci < NCHUNK; ++ci) m = fmaxf(m, row[ci * CS_STRIDE]);
        s = expf(m);
    }
    float mu = block_sum192(s, red, tid) * (1.f / P_);
    float d  = (tid < P_) ? (s - mu) : 0.f;
    float var = block_sum192(d * d, red, tid) * (1.f / P_);
    float bin = 0.f;
    if (tid < P_) {
        float norm = (s - mu) * rsqrtf(var + 1e-5f) * gamma[tid] + beta[tid];
        bin = (norm > 0.f) ? 1.f : 0.f;
    }
    float o0 = block_sum192((tid < P_) ? bin * lw[tid]      : 0.f, red, tid);
    float o1 = block_sum192((tid < P_) ? bin * lw[P_ + tid] : 0.f, red, tid);
    if (tid == 0) {
        out[b * 2 + 0] = o0 + lb[0];
        out[b * 2 + 1] = o1 + lb[1];
    }
}

extern "C" void kernel_launch(void* const* d_in, const int* in_sizes, int n_in,
                              void* d_out, int out_size, void* d_ws, size_t ws_size,
                              hipStream_t stream)
{
    const int*   docs  = (const int*)  d_in[0];
    const int*   dlens = (const int*)  d_in[1];
    const float* emb   = (const float*)d_in[2];
    const float* diags = (const float*)d_in[3];
    const float* bias  = (const float*)d_in[4];
    const float* wildc = (const float*)d_in[5];
    const float* gamma = (const float*)d_in[6];
    const float* beta  = (const float*)d_in[7];
    const float* lw    = (const float*)d_in[8];
    const float* lb    = (const float*)d_in[9];
    float* out = (float*)d_out;

    // ws layout: cw | cs | a_t | b_t
    const size_t cw_b = (size_t)V_ * CWS * 4;                 // 60,160,000
    const size_t cs_b = (size_t)B_ * NCHUNK * CS_STRIDE * 4;  // 655,360
    const size_t at_b = (size_t)NVG * NIT * TILE_U4 * 16;     // 25,722,880
    const size_t bt_b = (size_t)NJ  * NIT * TILE_U4 * 16;     // 983,040
    const size_t need = cw_b + cs_b + at_b + bt_b;

    char* base = (char*)d_ws;
    float* cw = (float*)base;
    float* cs = (float*)(base + cw_b);
    uint4* at = (uint4*)(base + cw_b + cs_b);
    uint4* bt = (uint4*)(base + cw_b + cs_b + at_b);

    if (ws_size >= need) {
        p12_split<<<NVG * 5 + NJ * NIT, 256, 0, stream>>>(emb, diags, at, bt);
        // 314 blocks: 157 v-groups x 2 n-halves (384 cols each)
        k1m_gemm<<<NVG * 2, 512, 0, stream>>>(at, bt, bias, wildc, cw);
    } else {
        dim3 g1((V_ + BM - 1) / BM, (NOUT + BN - 1) / BN);
        k1_gemm_cw<<<g1, 256, 0, stream>>>(emb, diags, bias, wildc, cw);
    }

    dim3 g2(NCHUNK, B_);
    k2_scan<<<g2, 192, 0, stream>>>(docs, dlens, cw, cs);
    k3_final<<<B_, 192, 0, stream>>>(cs, gamma, beta, lw, lb, out);
}

// Round 3
// 178.589 us; speedup vs baseline: 1.3156x; 1.3156x over previous
//
#include <hip/hip_runtime.h>
#include <hip/hip_bf16.h>
#include <hip/hip_fp16.h>
#include <math.h>

// Problem constants (from reference)
#define B_   64
#define L_   512
#define V_   20000
#define P_   150
#define M_   6
#define KDIM 300
#define NOUT 750          // P_ * (M_-1) used transition scores
#define CWS  752          // padded row stride (16B-aligned float4 rows)
#define NEGF (-1.0e9f)

// f32 fallback GEMM tiling
#define BM 128
#define BN 128
#define BK 16
#define LDP 132

// MFMA path constants
#define KP 320            // K padded: 10 tiles of 32
#define NIT 10            // K-iters
#define NVG 157           // v-groups of 128
#define NJ  6             // n-groups of 128
#define TILE_U4 1024      // uint4 per (group,it) tile: [s 2][q 4][row 128]
#define SA 1024.0f        // emb scale (keeps lo-split out of fp16 subnormals)
#define SB 16384.0f       // diags scale
#define INV24 (5.9604644775390625e-8f)   // 2^-24

// Scan chunking
#define TCHUNK 32
#define NCHUNK (L_ / TCHUNK)   // 16
#define WARM   5
#define CS_STRIDE 160
#define KVBUF 3           // k2 pipeline depth-2 -> 3 LDS buffers

typedef _Float16 f16x8 __attribute__((ext_vector_type(8)));
typedef float f32x16 __attribute__((ext_vector_type(16)));

__device__ __forceinline__ float logsigf(float x) {
    // matches jax: -softplus(-x) = min(x,0) - log1p(exp(-|x|))
    return fminf(x, 0.f) - log1pf(expf(-fabsf(x)));
}

// fast variant for k1m epilogue: v_exp_f32/v_log_f32, abs err ~6e-8 (flip-safe budget)
__device__ __forceinline__ float logsigf_fast(float x) {
    return fminf(x, 0.f) - __logf(1.f + __expf(-fabsf(x)));
}

// async global->LDS, 16 B per lane; LDS dst = wave-uniform base + lane*16
__device__ __forceinline__ void gload_lds16(const void* gp, void* lp) {
    __builtin_amdgcn_global_load_lds(
        (const __attribute__((address_space(1))) unsigned int*)gp,
        (__attribute__((address_space(3))) unsigned int*)lp, 16, 0, 0);
}

// ---------------- MFMA path ----------------

// P12 (fused p1+p2, one launch):
// blocks [0, NVG*5): emb [300][20000] -> fp16 hi/lo splits, DMA-tiled
//   a_t[g 157][it 10][s 2][q 4][row 128] uint4.
// blocks [NVG*5, NVG*5+60): diags (dpm-mapped, scaled) -> b_t[j 6][it 10][s2][q4][row128].
__global__ __launch_bounds__(256) void p12_split(
    const float* __restrict__ emb, const float* __restrict__ diags,
    uint4* __restrict__ a_t, uint4* __restrict__ b_t)
{
    __shared__ float T[64][132];
    const int t   = threadIdx.x;
    const int bid = blockIdx.x;

    if (bid < NVG * 5) {
        // ---- p1 part ----
        const int gx = bid % NVG;
        const int ky = bid / NVG;            // 0..4
        const int v0 = gx * 128;
        const int k0 = ky * 64;

        #pragma unroll
        for (int pass = 0; pass < 8; ++pass) {
            int flat = pass * 256 + t;
            int krow = flat >> 5;
            int c4   = (flat & 31) * 4;
            int kg   = k0 + krow;
            int v    = v0 + c4;
            float4 f = {0.f, 0.f, 0.f, 0.f};
            if (kg < KDIM && v + 3 < V_)
                f = *(const float4*)(emb + (size_t)kg * V_ + v);
            *(float4*)&T[krow][c4] = f;
        }
        __syncthreads();

        const int vv = t >> 1;
        const int kh = (t & 1) * 32;
        const int it = ky * 2 + (kh >> 5);
        const int v  = v0 + vv;
        if (v < V_) {
            union { ushort u[8]; uint4 q; } H[4], Lo[4];
            #pragma unroll
            for (int i = 0; i < 32; ++i) {
                float x = T[kh + i][vv] * SA;
                __half h = __float2half_rn(x);
                float rem = x - __half2float(h);
                H[i >> 3].u[i & 7]  = __half_as_ushort(h);
                Lo[i >> 3].u[i & 7] = __half_as_ushort(__float2half_rn(rem));
            }
            uint4* tile = a_t + ((size_t)gx * NIT + it) * TILE_U4;
            #pragma unroll
            for (int c = 0; c < 4; ++c) {
                tile[      c * 128 + vv] = H[c].q;
                tile[512 + c * 128 + vv] = Lo[c].q;
            }
        }
    } else {
        // ---- p2 part ----
        const int bidx = bid - NVG * 5;      // j*10 + it, 0..59
        const int it   = bidx % NIT;
        const int j    = bidx / NIT;
        const int row  = t >> 1;
        const int qh   = (t & 1) * 2;
        const int n    = j * 128 + row;
        const bool nok = (n < NOUT);
        const int pm   = nok ? ((n / 5) * 6 + (n % 5)) : 0;
        uint4* tile = b_t + (size_t)bidx * TILE_U4;
        #pragma unroll
        for (int qq = 0; qq < 2; ++qq) {
            int q = qh + qq;
            union { ushort u[8]; uint4 v; } H, Lo;
            #pragma unroll
            for (int e = 0; e < 8; ++e) {
                int k = it * 32 + q * 8 + e;
                float x = (nok && k < KDIM) ? diags[(size_t)pm * KDIM + k] * SB : 0.f;
                __half h = __float2half_rn(x);
                float rem = x - __half2float(h);
                H.u[e]  = __half_as_ushort(h);
                Lo.u[e] = __half_as_ushort(__float2half_rn(rem));
            }
            tile[      q * 128 + row] = H.v;
            tile[512 + q * 128 + row] = Lo.v;
        }
    }
}

// K1 (MFMA, round-4): C = a1@b1 + a1@b2 + a2@b1 (fp16 split-f32), 256x256 tile.
//
// Round-2 post-mortem: gload_lds DMA is queue-limited ~10 B/cyc/CU from L3 ->
// staging (307 MB total for 128x128 tiles) IS the 50 us.
// Round-3 post-mortem: reg-staging idea untested -- __launch_bounds__(512,2)
// capped VGPR at ~108 vs ~200 needed -> 170 MB scratch spill -> 140 us.
//
// This round: honest register budget.
//  - 256x256 tile: staged traffic 307 -> 154 MB. Grid 240 = 80 gp x 3 nb,
//    XCD-swizzled so the 3 n-siblings sharing an A-panel colocate per XCD
//    (bid%8 invariant) -> A re-reads are per-XCD L2 hits.
//  - 512 threads / 8 waves (2 row x 4 col), wave tile 128x64:
//    acc 4x2 f32x16 = 128 VGPR + frags 48 + ONE staging set 32 + addr ~16
//    = ~224 < 256 cap from __launch_bounds__(512) [no min-waves arg!].
//    1 block/CU (LDS 128 KB), 2 waves/SIMD.
//  - Reg staging via plain global_load_dwordx4 (in-flight scales with waves;
//    DMA engine bypassed). Loads for it+2 issue BEFORE the MFMA phase of it;
//    ds_write frees the regs at issue; one __syncthreads/iter whose vmcnt(0)
//    drain sits behind a full ~3k-cyc compute phase -> free.
//  - NT stores reverted (cost ~4 us in k2 via L3 bypass; no k1m gain).
// Accumulation order per output element identical -> bitwise-same C.
__global__ __launch_bounds__(512) void k1m_gemm(
    const uint4* __restrict__ a_t, const uint4* __restrict__ b_t,
    const float* __restrict__ bias, const float* __restrict__ wildc,
    float* __restrict__ cw)
{
    const int bid = blockIdx.x;              // 0..239
    const int c   = bid / 24;                // gp-chunk 0..9
    const int r   = bid % 24;
    const int gp  = c * 8 + (r & 7);         // 256-row group-pair 0..79
    const int h   = r >> 3;                  // n-block 0..2 (256 cols each)
    if (gp >= 79) return;                    // gp=78 partial (v guard below)

    __shared__ uint4 sm[2][4096];            // 2 x 64 KB
    const int t    = threadIdx.x;            // 0..511
    const int lane = t & 63;
    const int w    = t >> 6;                 // wave 0..7
    const int wr   = w >> 2;                 // 128-row half
    const int wc   = w & 3;                  // 64-col quarter
    const int fk16 = lane >> 5;
    const int fm   = lane & 31;

    const int ga = 2 * gp;
    const int gb = (2 * gp + 1 < NVG) ? (2 * gp + 1) : (NVG - 1); // clamp (dup rows discarded by v<V_)
    const uint4* abase0 = a_t + (size_t)ga * NIT * TILE_U4;
    const uint4* abase1 = a_t + (size_t)gb * NIT * TILE_U4;
    const uint4* bbase0 = b_t + (size_t)(2 * h)     * NIT * TILE_U4;
    const uint4* bbase1 = b_t + (size_t)(2 * h + 1) * NIT * TILE_U4;

    f32x16 acc[4][2];
    #pragma unroll
    for (int i = 0; i < 4; ++i)
        #pragma unroll
        for (int jj = 0; jj < 2; ++jj)
            #pragma unroll
            for (int e = 0; e < 16; ++e) acc[i][jj][e] = 0.f;

    uint4 rg[8];                             // single staging set (32 VGPR)

    // 8 x 16 B per thread per iter: A 32 KB (2 groups) + B 32 KB (2 n-groups)
    #define LOAD_SET(IT)                                   \
        do {                                               \
            const size_t o = (size_t)(IT) * TILE_U4;       \
            rg[0] = abase0[o + t];                         \
            rg[1] = abase0[o + 512 + t];                   \
            rg[2] = abase1[o + t];                         \
            rg[3] = abase1[o + 512 + t];                   \
            rg[4] = bbase0[o + t];                         \
            rg[5] = bbase0[o + 512 + t];                   \
            rg[6] = bbase1[o + t];                         \
            rg[7] = bbase1[o + 512 + t];                   \
        } while (0)

    // LDS layout per buffer (4096 u4): A-grp0 | A-grp1 | B-j-even | B-j-odd,
    // each 1024 u4 in the native tile layout [part 2][q 4][row 128].
    #define WRITE_SET(BSEL)                                \
        do {                                               \
            uint4* smb = &sm[(BSEL)][0];                   \
            smb[        t] = rg[0];                        \
            smb[ 512 +  t] = rg[1];                        \
            smb[1024 +  t] = rg[2];                        \
            smb[1536 +  t] = rg[3];                        \
            smb[2048 +  t] = rg[4];                        \
            smb[2560 +  t] = rg[5];                        \
            smb[3072 +  t] = rg[6];                        \
            smb[3584 +  t] = rg[7];                        \
        } while (0)

    // prologue: stage it=0, issue it=1 (one ~latency stall at iter-0 top only)
    LOAD_SET(0);
    WRITE_SET(0);          // compiler waits the rg vmcnt automatically
    LOAD_SET(1);
    __syncthreads();

    #pragma unroll
    for (int it = 0; it < NIT; ++it) {
        // 1) stage data(it+1) (loaded last iter; barrier already drained it)
        if (it + 1 < NIT) WRITE_SET((it + 1) & 1);
        // 2) issue loads for it+2 (regs free after ds_write issue); they land
        //    during this iter's MFMA phase, drained by the end-of-iter barrier
        if (it + 2 < NIT) LOAD_SET(it + 2);

        // 3) compute iter it from sm[it&1]
        const uint4* smc = &sm[it & 1][0];
        #pragma unroll
        for (int s = 0; s < 2; ++s) {
            const int q = s * 2 + fk16;
            f16x8 A1[4], A2[4], B1[2], B2[2];
            #pragma unroll
            for (int ri = 0; ri < 4; ++ri) {
                const int ao = wr * 1024 + q * 128 + ri * 32 + fm;
                A1[ri] = *(const f16x8*)&smc[ao];
                A2[ri] = *(const f16x8*)&smc[ao + 512];
            }
            #pragma unroll
            for (int cj = 0; cj < 2; ++cj) {
                const int colb = wc * 64 + cj * 32;
                const int bo = 2048 + (colb >> 7) * 1024 + q * 128 + (colb & 127) + fm;
                B1[cj] = *(const f16x8*)&smc[bo];
                B2[cj] = *(const f16x8*)&smc[bo + 512];
            }
            #pragma unroll
            for (int ri = 0; ri < 4; ++ri)
                #pragma unroll
                for (int cj = 0; cj < 2; ++cj) {
                    acc[ri][cj] = __builtin_amdgcn_mfma_f32_32x32x16_f16(A1[ri], B1[cj], acc[ri][cj], 0, 0, 0);
                    acc[ri][cj] = __builtin_amdgcn_mfma_f32_32x32x16_f16(A1[ri], B2[cj], acc[ri][cj], 0, 0, 0);
                    acc[ri][cj] = __builtin_amdgcn_mfma_f32_32x32x16_f16(A2[ri], B1[cj], acc[ri][cj], 0, 0, 0);
                }
        }

        if (it + 1 < NIT) __syncthreads();
    }
    #undef LOAD_SET
    #undef WRITE_SET

    // epilogue: C/D layout col=lane&31, row=(r&3)+8*(r>>2)+4*(lane>>5)
    float biasv[2], lwv[2]; int ncol[2]; bool nok[2];
    #pragma unroll
    for (int cj = 0; cj < 2; ++cj) {
        int n = h * 256 + wc * 64 + cj * 32 + fm;
        ncol[cj] = n;
        nok[cj]  = (n < NOUT);
        int nc = nok[cj] ? n : 0;
        int pm = (nc / 5) * 6 + (nc % 5);
        biasv[cj] = bias[pm];
        lwv[cj]   = logsigf_fast(wildc[nc]);
    }
    const int v0 = gp * 256;
    #pragma unroll
    for (int ri = 0; ri < 4; ++ri) {
        int vbase = v0 + wr * 128 + ri * 32 + 4 * fk16;
        #pragma unroll
        for (int cj = 0; cj < 2; ++cj) {
            if (!nok[cj]) continue;
            #pragma unroll
            for (int e = 0; e < 16; ++e) {
                int v = vbase + (e & 3) + 8 * (e >> 2);
                if (v < V_) {
                    float val = acc[ri][cj][e] * INV24 + biasv[cj];
                    cw[(size_t)v * CWS + ncol[cj]] = fmaxf(logsigf_fast(val), lwv[cj]);
                }
            }
        }
    }
}

// ---------------- f32 fallback (round-2 kernel) ----------------

__global__ __launch_bounds__(256) void k1_gemm_cw(
    const float* __restrict__ emb,
    const float* __restrict__ diags,
    const float* __restrict__ bias,
    const float* __restrict__ wildc,
    float* __restrict__ cw)
{
    __shared__ float As[BK][LDP];
    __shared__ float Bs[BK][LDP];

    const int tid = threadIdx.x;
    const int v0 = blockIdx.x * BM;
    const int n0 = blockIdx.y * BN;
    const int tx = tid & 15;
    const int ty = tid >> 4;

    float acc[8][8];
    #pragma unroll
    for (int i = 0; i < 8; ++i)
        #pragma unroll
        for (int j = 0; j < 8; ++j) acc[i][j] = 0.f;

    const int a_k = tid >> 4;
    const int a_v = (tid & 15) * 8;
    const int b_n   = tid >> 1;
    const int b_kof = (tid & 1) * 8;

    int  brow;
    bool bval;
    {
        int n = n0 + b_n;
        bval = (n < NOUT);
        brow = bval ? ((n / 5) * 6 + (n % 5)) : 0;
    }

    for (int k0 = 0; k0 < KDIM; k0 += BK) {
        {
            float4 f0 = {0,0,0,0}, f1 = {0,0,0,0};
            int k = k0 + a_k;
            if (k < KDIM) {
                const float* src = emb + (size_t)k * V_ + v0 + a_v;
                if (v0 + a_v + 3 < V_) f0 = *(const float4*)src;
                if (v0 + a_v + 7 < V_) f1 = *(const float4*)(src + 4);
            }
            *(float4*)&As[a_k][a_v]     = f0;
            *(float4*)&As[a_k][a_v + 4] = f1;
        }
        {
            float4 f = {0,0,0,0}, g = {0,0,0,0};
            if (bval) {
                const float* src = diags + (size_t)brow * KDIM + k0 + b_kof;
                if (k0 + b_kof + 3 < KDIM) f = *(const float4*)src;
                if (k0 + b_kof + 7 < KDIM) g = *(const float4*)(src + 4);
            }
            Bs[b_kof + 0][b_n] = f.x;
            Bs[b_kof + 1][b_n] = f.y;
            Bs[b_kof + 2][b_n] = f.z;
            Bs[b_kof + 3][b_n] = f.w;
            Bs[b_kof + 4][b_n] = g.x;
            Bs[b_kof + 5][b_n] = g.y;
            Bs[b_kof + 6][b_n] = g.z;
            Bs[b_kof + 7][b_n] = g.w;
        }
        __syncthreads();
        #pragma unroll
        for (int k = 0; k < BK; ++k) {
            float4 a0 = *(const float4*)&As[k][tx * 4];
            float4 a1 = *(const float4*)&As[k][64 + tx * 4];
            float4 b0 = *(const float4*)&Bs[k][ty * 8];
            float4 b1 = *(const float4*)&Bs[k][ty * 8 + 4];
            float av[8] = {a0.x, a0.y, a0.z, a0.w, a1.x, a1.y, a1.z, a1.w};
            float bv[8] = {b0.x, b0.y, b0.z, b0.w, b1.x, b1.y, b1.z, b1.w};
            #pragma unroll
            for (int i = 0; i < 8; ++i)
                #pragma unroll
                for (int j = 0; j < 8; ++j)
                    acc[i][j] = fmaf(av[i], bv[j], acc[i][j]);
        }
        __syncthreads();
    }

    float biasv[8], lwv[8];
    #pragma unroll
    for (int j = 0; j < 8; ++j) {
        int n  = n0 + ty * 8 + j;
        int nc = (n < NOUT) ? n : 0;
        int pm = (nc / 5) * 6 + (nc % 5);
        biasv[j] = bias[pm];
        lwv[j]   = logsigf(wildc[nc]);
    }
    #pragma unroll
    for (int i = 0; i < 8; ++i) {
        int v = v0 + ((i < 4) ? (tx * 4 + i) : (64 + tx * 4 + (i - 4)));
        if (v >= V_) continue;
        float r[8];
        #pragma unroll
        for (int j = 0; j < 8; ++j)
            r[j] = fmaxf(logsigf(acc[i][j] + biasv[j]), lwv[j]);
        float* dst = cw + (size_t)v * CWS + n0 + ty * 8;
        if (n0 + ty * 8     < NOUT) *(float4*)dst       = make_float4(r[0], r[1], r[2], r[3]);
        if (n0 + ty * 8 + 4 < NOUT) *(float4*)(dst + 4) = make_float4(r[4], r[5], r[6], r[7]);
    }
}

// ---------------- scan (pipelined LDS staging) + finalize ----------------

// 3-buffer, depth-2 pipeline with counted s_waitcnt vmcnt(3) + raw s_barrier
// (one barrier per round). Bit-identical values.
__global__ __launch_bounds__(192) void k2_scan(
    const int* __restrict__ docs,
    const int* __restrict__ doc_lens,
    const float* __restrict__ cw,
    float* __restrict__ cs)
{
    const int ci = blockIdx.x;
    const int b  = blockIdx.y;
    const int t0 = ci * TCHUNK;
    const int ts = (t0 >= WARM) ? (t0 - WARM) : 0;
    const int dl = doc_lens[b];
    const int te = min(t0 + TCHUNK, dl);
    const int nt = te - ts;              // tokens to process (may be <= 0)

    __shared__ int   toks[TCHUNK + WARM];
    __shared__ float rows[KVBUF][3][768];   // 27 KB: [buf][row-in-round][752 used]

    const int t    = threadIdx.x;
    const int lane = t & 63;
    const int w    = t >> 6;             // wave 0..2

    if (t < TCHUNK + WARM) {
        int tt = ts + t;
        toks[t] = docs[b * L_ + min(tt, L_ - 1)];
    }
    __syncthreads();                     // toks ready; drains all prior vmem

    const int p      = t;                // pattern if < P_
    const int e      = (p < 50) ? 3 : (p < 100) ? 4 : 5;
    const int warm_n = t0 - ts;
    float h1 = NEGF, h2 = NEGF, h3 = NEGF, h4 = NEGF, h5 = NEGF, sc = NEGF;

    const int nrounds = (nt > 0) ? (nt + 2) / 3 : 0;

    // prologue: issue DMA for rounds 0 and 1 (wave w stages row w of a round)
    for (int r0 = 0; r0 < 2; ++r0) {
        if (r0 >= nrounds) break;
        int idx = min(3 * r0 + w, nt - 1);
        const char* rowp = (const char*)(cw + (size_t)toks[idx] * CWS);
        char* lbase = (char*)&rows[r0][w][0];
        #pragma unroll
        for (int jj = 0; jj < 3; ++jj)
            gload_lds16(rowp + jj * 1024 + lane * 16,
                        lbase + jj * 1024 + lane * 16);
    }

    int bufc = 0;
    for (int r = 0; r < nrounds; ++r) {
        // drain THIS round's DMA only; keep round r+1's 3 loads in flight
        if (r + 1 < nrounds) {
            asm volatile("s_waitcnt vmcnt(3)" ::: "memory");
        } else {
            asm volatile("s_waitcnt vmcnt(0)" ::: "memory");
        }
        __builtin_amdgcn_s_barrier();
        asm volatile("" ::: "memory");   // fence: no rows-read hoists above barrier

        if (r + 2 < nrounds) {           // prefetch round r+2 (buffer of round r-1)
            int rn  = r + 2;
            int idx = min(3 * rn + w, nt - 1);
            const char* rowp = (const char*)(cw + (size_t)toks[idx] * CWS);
            int bn = bufc + 2; if (bn >= KVBUF) bn -= KVBUF;
            char* lbase = (char*)&rows[bn][w][0];
            #pragma unroll
            for (int jj = 0; jj < 3; ++jj)
                gload_lds16(rowp + jj * 1024 + lane * 16,
                            lbase + jj * 1024 + lane * 16);
        }

        #pragma unroll
        for (int u = 0; u < 3; ++u) {
            int i2 = 3 * r + u;
            if (i2 >= nt) break;
            if (p < P_) {
                const float* rp = &rows[bufc][u][p * 5];
                float c0 = rp[0], c1 = rp[1], c2 = rp[2], c3 = rp[3], c4 = rp[4];
                h5 = h4 + c4;
                h4 = h3 + c3;
                h3 = h2 + c2;
                h2 = h1 + c1;
                h1 = c0;                 // h0 = 0 always
                if (i2 >= warm_n) {
                    float esv = (e == 3) ? h3 : (e == 4) ? h4 : h5;
                    sc = fmaxf(sc, esv);
                }
            }
        }
        bufc = (bufc + 1 == KVBUF) ? 0 : bufc + 1;
        // no second barrier: the barrier at top of round r+1 orders
        // compute(r) (all waves) before DMA(r+3) overwrites buf[r%3]
    }
    if (p < P_) cs[(size_t)(b * NCHUNK + ci) * CS_STRIDE + p] = sc;
}

__device__ __forceinline__ float block_sum192(float v, volatile float* red, int tid) {
    #pragma unroll
    for (int off = 32; off > 0; off >>= 1) v += __shfl_down(v, off, 64);
    __syncthreads();
    if ((tid & 63) == 0) red[tid >> 6] = v;
    __syncthreads();
    return red[0] + red[1] + red[2];
}

__global__ __launch_bounds__(192) void k3_final(
    const float* __restrict__ cs,
    const float* __restrict__ gamma,
    const float* __restrict__ beta,
    const float* __restrict__ lw,
    const float* __restrict__ lb,
    float* __restrict__ out)
{
    __shared__ float red[3];
    const int b   = blockIdx.x;
    const int tid = threadIdx.x;
    float s = 0.f;
    if (tid < P_) {
        float m = NEGF;
        const float* row = cs + (size_t)b * NCHUNK * CS_STRIDE + tid;
        #pragma unroll
        for (int ci = 0; ci < NCHUNK; ++ci) m = fmaxf(m, row[ci * CS_STRIDE]);
        s = expf(m);
    }
    float mu = block_sum192(s, red, tid) * (1.f / P_);
    float d  = (tid < P_) ? (s - mu) : 0.f;
    float var = block_sum192(d * d, red, tid) * (1.f / P_);
    float bin = 0.f;
    if (tid < P_) {
        float norm = (s - mu) * rsqrtf(var + 1e-5f) * gamma[tid] + beta[tid];
        bin = (norm > 0.f) ? 1.f : 0.f;
    }
    float o0 = block_sum192((tid < P_) ? bin * lw[tid]      : 0.f, red, tid);
    float o1 = block_sum192((tid < P_) ? bin * lw[P_ + tid] : 0.f, red, tid);
    if (tid == 0) {
        out[b * 2 + 0] = o0 + lb[0];
        out[b * 2 + 1] = o1 + lb[1];
    }
}

extern "C" void kernel_launch(void* const* d_in, const int* in_sizes, int n_in,
                              void* d_out, int out_size, void* d_ws, size_t ws_size,
                              hipStream_t stream)
{
    const int*   docs  = (const int*)  d_in[0];
    const int*   dlens = (const int*)  d_in[1];
    const float* emb   = (const float*)d_in[2];
    const float* diags = (const float*)d_in[3];
    const float* bias  = (const float*)d_in[4];
    const float* wildc = (const float*)d_in[5];
    const float* gamma = (const float*)d_in[6];
    const float* beta  = (const float*)d_in[7];
    const float* lw    = (const float*)d_in[8];
    const float* lb    = (const float*)d_in[9];
    float* out = (float*)d_out;

    // ws layout: cw | cs | a_t | b_t
    const size_t cw_b = (size_t)V_ * CWS * 4;                 // 60,160,000
    const size_t cs_b = (size_t)B_ * NCHUNK * CS_STRIDE * 4;  // 655,360
    const size_t at_b = (size_t)NVG * NIT * TILE_U4 * 16;     // 25,722,880
    const size_t bt_b = (size_t)NJ  * NIT * TILE_U4 * 16;     // 983,040
    const size_t need = cw_b + cs_b + at_b + bt_b;

    char* base = (char*)d_ws;
    float* cw = (float*)base;
    float* cs = (float*)(base + cw_b);
    uint4* at = (uint4*)(base + cw_b + cs_b);
    uint4* bt = (uint4*)(base + cw_b + cs_b + at_b);

    if (ws_size >= need) {
        p12_split<<<NVG * 5 + NJ * NIT, 256, 0, stream>>>(emb, diags, at, bt);
        // 240 blocks: 80 group-pair chunks x 3 n-blocks, XCD-colocated siblings
        k1m_gemm<<<240, 512, 0, stream>>>(at, bt, bias, wildc, cw);
    } else {
        dim3 g1((V_ + BM - 1) / BM, (NOUT + BN - 1) / BN);
        k1_gemm_cw<<<g1, 256, 0, stream>>>(emb, diags, bias, wildc, cw);
    }

    dim3 g2(NCHUNK, B_);
    k2_scan<<<g2, 192, 0, stream>>>(docs, dlens, cw, cs);
    k3_final<<<B_, 192, 0, stream>>>(cs, gamma, beta, lw, lb, out);
}

// Round 4
// 148.484 us; speedup vs baseline: 1.5823x; 1.2028x over previous
//
#include <hip/hip_runtime.h>
#include <hip/hip_bf16.h>
#include <hip/hip_fp16.h>
#include <math.h>

// Problem constants (from reference)
#define B_   64
#define L_   512
#define V_   20000
#define P_   150
#define M_   6
#define KDIM 300
#define NOUT 750          // P_ * (M_-1) used transition scores
#define CWS  752          // padded row stride (16B-aligned float4 rows)
#define NEGF (-1.0e9f)

// f32 fallback GEMM tiling
#define BM 128
#define BN 128
#define BK 16
#define LDP 132

// MFMA path constants
#define KP 320            // K padded: 10 tiles of 32
#define NIT 10            // K-iters
#define NVG 157           // v-groups of 128
#define NJ  6             // n-groups of 128
#define TILE_U4 1024      // uint4 per (group,it) tile: [s 2][q 4][row 128]
#define SA 1024.0f        // emb scale (keeps lo-split out of fp16 subnormals)
#define SB 16384.0f       // diags scale
#define INV24 (5.9604644775390625e-8f)   // 2^-24

// Scan chunking
#define TCHUNK 32
#define NCHUNK (L_ / TCHUNK)   // 16
#define WARM   5
#define CS_STRIDE 160
#define KVBUF 3           // k2 pipeline depth-2 -> 3 LDS buffers

typedef _Float16 f16x8 __attribute__((ext_vector_type(8)));
typedef float f32x16 __attribute__((ext_vector_type(16)));

__device__ __forceinline__ float logsigf(float x) {
    // matches jax: -softplus(-x) = min(x,0) - log1p(exp(-|x|))
    return fminf(x, 0.f) - log1pf(expf(-fabsf(x)));
}

// fast variant for k1m epilogue: v_exp_f32/v_log_f32, abs err ~6e-8 (flip-safe budget)
__device__ __forceinline__ float logsigf_fast(float x) {
    return fminf(x, 0.f) - __logf(1.f + __expf(-fabsf(x)));
}

// async global->LDS, 16 B per lane; LDS dst = wave-uniform base + lane*16
__device__ __forceinline__ void gload_lds16(const void* gp, void* lp) {
    __builtin_amdgcn_global_load_lds(
        (const __attribute__((address_space(1))) unsigned int*)gp,
        (__attribute__((address_space(3))) unsigned int*)lp, 16, 0, 0);
}

// ---------------- MFMA path ----------------

// P12 (fused p1+p2, one launch):
// blocks [0, NVG*5): emb [300][20000] -> fp16 hi/lo splits, DMA-tiled
//   a_t[g 157][it 10][s 2][q 4][row 128] uint4.
// blocks [NVG*5, NVG*5+60): diags (dpm-mapped, scaled) -> b_t[j 6][it 10][s2][q4][row128].
__global__ __launch_bounds__(256) void p12_split(
    const float* __restrict__ emb, const float* __restrict__ diags,
    uint4* __restrict__ a_t, uint4* __restrict__ b_t)
{
    __shared__ float T[64][132];
    const int t   = threadIdx.x;
    const int bid = blockIdx.x;

    if (bid < NVG * 5) {
        // ---- p1 part ----
        const int gx = bid % NVG;
        const int ky = bid / NVG;            // 0..4
        const int v0 = gx * 128;
        const int k0 = ky * 64;

        #pragma unroll
        for (int pass = 0; pass < 8; ++pass) {
            int flat = pass * 256 + t;
            int krow = flat >> 5;
            int c4   = (flat & 31) * 4;
            int kg   = k0 + krow;
            int v    = v0 + c4;
            float4 f = {0.f, 0.f, 0.f, 0.f};
            if (kg < KDIM && v + 3 < V_)
                f = *(const float4*)(emb + (size_t)kg * V_ + v);
            *(float4*)&T[krow][c4] = f;
        }
        __syncthreads();

        const int vv = t >> 1;
        const int kh = (t & 1) * 32;
        const int it = ky * 2 + (kh >> 5);
        const int v  = v0 + vv;
        if (v < V_) {
            union { ushort u[8]; uint4 q; } H[4], Lo[4];
            #pragma unroll
            for (int i = 0; i < 32; ++i) {
                float x = T[kh + i][vv] * SA;
                __half h = __float2half_rn(x);
                float rem = x - __half2float(h);
                H[i >> 3].u[i & 7]  = __half_as_ushort(h);
                Lo[i >> 3].u[i & 7] = __half_as_ushort(__float2half_rn(rem));
            }
            uint4* tile = a_t + ((size_t)gx * NIT + it) * TILE_U4;
            #pragma unroll
            for (int c = 0; c < 4; ++c) {
                tile[      c * 128 + vv] = H[c].q;
                tile[512 + c * 128 + vv] = Lo[c].q;
            }
        }
    } else {
        // ---- p2 part ----
        const int bidx = bid - NVG * 5;      // j*10 + it, 0..59
        const int it   = bidx % NIT;
        const int j    = bidx / NIT;
        const int row  = t >> 1;
        const int qh   = (t & 1) * 2;
        const int n    = j * 128 + row;
        const bool nok = (n < NOUT);
        const int pm   = nok ? ((n / 5) * 6 + (n % 5)) : 0;
        uint4* tile = b_t + (size_t)bidx * TILE_U4;
        #pragma unroll
        for (int qq = 0; qq < 2; ++qq) {
            int q = qh + qq;
            union { ushort u[8]; uint4 v; } H, Lo;
            #pragma unroll
            for (int e = 0; e < 8; ++e) {
                int k = it * 32 + q * 8 + e;
                float x = (nok && k < KDIM) ? diags[(size_t)pm * KDIM + k] * SB : 0.f;
                __half h = __float2half_rn(x);
                float rem = x - __half2float(h);
                H.u[e]  = __half_as_ushort(h);
                Lo.u[e] = __half_as_ushort(__float2half_rn(rem));
            }
            tile[      q * 128 + row] = H.v;
            tile[512 + q * 128 + row] = Lo.v;
        }
    }
}

// K1 (MFMA, round-5): C = a1@b1 + a1@b2 + a2@b1 (fp16 split-f32), 256x256 tile,
// gload_lds staging (round-0's proven mechanism) + pinned occupancy.
//
// History:
//  r0/r1: 128x128, gload_lds, 2 blk/CU -> 50 us, staging-limited (295 MB
//         staged at ~10 B/cyc/CU DMA from L3; FETCH only 16.6 MB -> not HBM).
//  r2/r3: reg-staging rewrites both SPILLED: the backend targets 4 waves/EU
//         (VGPR budget 108/128) even though 128 KB LDS caps at 2 waves/EU.
//         WRITE_SIZE 141-232 MB of scratch, 78-140 us. Lesson: must pin the
//         occupancy target to get the 256-VGPR budget.
//  r4 (this): 256x256 tile halves staged volume (154 MB); staging via
//         gload_lds (NO staging registers); amdgpu_waves_per_eu(2,2) pins
//         budget at 256 VGPR for acc 128 + frags 48 (~200 live). 8 waves
//         (2 row x 4 col), wave tile 128x64. One barrier/iter, double-buffer.
//         XCD-swizzle: blocks r, r+8, r+16 of a 24-chunk share gp on one XCD.
// Spill check: WRITE_SIZE must be ~61-63 MB (cw only). Accumulation order per
// output element identical to r0-r3 -> bitwise-same C.
__global__ __attribute__((amdgpu_waves_per_eu(2, 2))) __launch_bounds__(512)
void k1m_gemm(
    const uint4* __restrict__ a_t, const uint4* __restrict__ b_t,
    const float* __restrict__ bias, const float* __restrict__ wildc,
    float* __restrict__ cw)
{
    const int bid = blockIdx.x;              // 0..239
    const int c   = bid / 24;                // gp-chunk 0..9
    const int r   = bid % 24;
    const int gp  = c * 8 + (r & 7);         // 256-row group-pair 0..79
    const int h   = r >> 3;                  // n-block 0..2 (256 cols each)
    if (gp >= 79) return;                    // gp=79 invalid (3 idle blocks)

    __shared__ uint4 sm[2][4096];            // 2 x 64 KB
    const int t    = threadIdx.x;            // 0..511
    const int lane = t & 63;
    const int w    = t >> 6;                 // wave 0..7
    const int wr   = w >> 2;                 // 128-row half (== A group select)
    const int wc   = w & 3;                  // 64-col quarter
    const int fk16 = lane >> 5;
    const int fm   = lane & 31;

    const int ga = 2 * gp;
    const int gb = (2 * gp + 1 < NVG) ? (2 * gp + 1) : (NVG - 1); // clamp; dup rows guarded at write
    // wave w stages 8 KB section w of each 64 KB iter-stage:
    //   sections 0-1: A-g0 hi|lo, 2-3: A-g1 hi|lo, 4-5: B-j0 hi|lo, 6-7: B-j1 hi|lo
    const int sel  = w >> 1;
    const int half = w & 1;
    const uint4* gsec =
        ((sel == 0) ? a_t + (size_t)ga * NIT * TILE_U4 :
         (sel == 1) ? a_t + (size_t)gb * NIT * TILE_U4 :
         (sel == 2) ? b_t + (size_t)(2 * h)     * NIT * TILE_U4 :
                      b_t + (size_t)(2 * h + 1) * NIT * TILE_U4) + half * 512;

    f32x16 acc[4][2];
    #pragma unroll
    for (int i = 0; i < 4; ++i)
        #pragma unroll
        for (int jj = 0; jj < 2; ++jj)
            #pragma unroll
            for (int e = 0; e < 16; ++e) acc[i][jj][e] = 0.f;

    // prologue: stage it=0 into buffer 0 (8 x 1 KB per wave)
    {
        const uint4* gp0 = gsec + lane;
        #pragma unroll
        for (int i = 0; i < 8; ++i)
            gload_lds16(gp0 + i * 64, &sm[0][w * 512 + i * 64 + lane]);
    }

    int cur = 0;
    for (int it = 0; it < NIT; ++it) {
        __syncthreads();                     // drains DMA for buf[cur]; fences prev compute

        if (it + 1 < NIT) {                  // async prefetch into the other buffer
            const uint4* gpp = gsec + (size_t)(it + 1) * TILE_U4 + lane;
            #pragma unroll
            for (int i = 0; i < 8; ++i)
                gload_lds16(gpp + i * 64, &sm[cur ^ 1][w * 512 + i * 64 + lane]);
        }

        // compute iter it from sm[cur]
        // LDS layout per buffer (u4): [A-g0 1024][A-g1 1024][B-j0 1024][B-j1 1024],
        // each tile native [s 2][q 4][row 128].
        const uint4* smc = &sm[cur][0];
        #pragma unroll
        for (int s = 0; s < 2; ++s) {
            const int q = s * 2 + fk16;
            f16x8 A1[4], A2[4], B1[2], B2[2];
            #pragma unroll
            for (int ri = 0; ri < 4; ++ri) {
                const int ao = wr * 1024 + q * 128 + ri * 32 + fm;
                A1[ri] = *(const f16x8*)&smc[ao];
                A2[ri] = *(const f16x8*)&smc[ao + 512];
            }
            #pragma unroll
            for (int cj = 0; cj < 2; ++cj) {
                const int colb = wc * 64 + cj * 32;
                const int bo = 2048 + (colb >> 7) * 1024 + q * 128 + (colb & 127) + fm;
                B1[cj] = *(const f16x8*)&smc[bo];
                B2[cj] = *(const f16x8*)&smc[bo + 512];
            }
            #pragma unroll
            for (int ri = 0; ri < 4; ++ri)
                #pragma unroll
                for (int cj = 0; cj < 2; ++cj) {
                    acc[ri][cj] = __builtin_amdgcn_mfma_f32_32x32x16_f16(A1[ri], B1[cj], acc[ri][cj], 0, 0, 0);
                    acc[ri][cj] = __builtin_amdgcn_mfma_f32_32x32x16_f16(A1[ri], B2[cj], acc[ri][cj], 0, 0, 0);
                    acc[ri][cj] = __builtin_amdgcn_mfma_f32_32x32x16_f16(A2[ri], B1[cj], acc[ri][cj], 0, 0, 0);
                }
        }
        cur ^= 1;
    }

    // epilogue: C/D layout col=lane&31, row=(e&3)+8*(e>>2)+4*(lane>>5)
    float biasv[2], lwv[2]; int ncol[2]; bool nok[2];
    #pragma unroll
    for (int cj = 0; cj < 2; ++cj) {
        int n = h * 256 + wc * 64 + cj * 32 + fm;
        ncol[cj] = n;
        nok[cj]  = (n < NOUT);
        int nc = nok[cj] ? n : 0;
        int pm = (nc / 5) * 6 + (nc % 5);
        biasv[cj] = bias[pm];
        lwv[cj]   = logsigf_fast(wildc[nc]);
    }
    const int v0 = gp * 256;
    #pragma unroll
    for (int ri = 0; ri < 4; ++ri) {
        int vbase = v0 + wr * 128 + ri * 32 + 4 * fk16;
        #pragma unroll
        for (int cj = 0; cj < 2; ++cj) {
            if (!nok[cj]) continue;
            #pragma unroll
            for (int e = 0; e < 16; ++e) {
                int v = vbase + (e & 3) + 8 * (e >> 2);
                if (v < V_) {
                    float val = acc[ri][cj][e] * INV24 + biasv[cj];
                    cw[(size_t)v * CWS + ncol[cj]] = fmaxf(logsigf_fast(val), lwv[cj]);
                }
            }
        }
    }
}

// ---------------- f32 fallback (round-2 kernel) ----------------

__global__ __launch_bounds__(256) void k1_gemm_cw(
    const float* __restrict__ emb,
    const float* __restrict__ diags,
    const float* __restrict__ bias,
    const float* __restrict__ wildc,
    float* __restrict__ cw)
{
    __shared__ float As[BK][LDP];
    __shared__ float Bs[BK][LDP];

    const int tid = threadIdx.x;
    const int v0 = blockIdx.x * BM;
    const int n0 = blockIdx.y * BN;
    const int tx = tid & 15;
    const int ty = tid >> 4;

    float acc[8][8];
    #pragma unroll
    for (int i = 0; i < 8; ++i)
        #pragma unroll
        for (int j = 0; j < 8; ++j) acc[i][j] = 0.f;

    const int a_k = tid >> 4;
    const int a_v = (tid & 15) * 8;
    const int b_n   = tid >> 1;
    const int b_kof = (tid & 1) * 8;

    int  brow;
    bool bval;
    {
        int n = n0 + b_n;
        bval = (n < NOUT);
        brow = bval ? ((n / 5) * 6 + (n % 5)) : 0;
    }

    for (int k0 = 0; k0 < KDIM; k0 += BK) {
        {
            float4 f0 = {0,0,0,0}, f1 = {0,0,0,0};
            int k = k0 + a_k;
            if (k < KDIM) {
                const float* src = emb + (size_t)k * V_ + v0 + a_v;
                if (v0 + a_v + 3 < V_) f0 = *(const float4*)src;
                if (v0 + a_v + 7 < V_) f1 = *(const float4*)(src + 4);
            }
            *(float4*)&As[a_k][a_v]     = f0;
            *(float4*)&As[a_k][a_v + 4] = f1;
        }
        {
            float4 f = {0,0,0,0}, g = {0,0,0,0};
            if (bval) {
                const float* src = diags + (size_t)brow * KDIM + k0 + b_kof;
                if (k0 + b_kof + 3 < KDIM) f = *(const float4*)src;
                if (k0 + b_kof + 7 < KDIM) g = *(const float4*)(src + 4);
            }
            Bs[b_kof + 0][b_n] = f.x;
            Bs[b_kof + 1][b_n] = f.y;
            Bs[b_kof + 2][b_n] = f.z;
            Bs[b_kof + 3][b_n] = f.w;
            Bs[b_kof + 4][b_n] = g.x;
            Bs[b_kof + 5][b_n] = g.y;
            Bs[b_kof + 6][b_n] = g.z;
            Bs[b_kof + 7][b_n] = g.w;
        }
        __syncthreads();
        #pragma unroll
        for (int k = 0; k < BK; ++k) {
            float4 a0 = *(const float4*)&As[k][tx * 4];
            float4 a1 = *(const float4*)&As[k][64 + tx * 4];
            float4 b0 = *(const float4*)&Bs[k][ty * 8];
            float4 b1 = *(const float4*)&Bs[k][ty * 8 + 4];
            float av[8] = {a0.x, a0.y, a0.z, a0.w, a1.x, a1.y, a1.z, a1.w};
            float bv[8] = {b0.x, b0.y, b0.z, b0.w, b1.x, b1.y, b1.z, b1.w};
            #pragma unroll
            for (int i = 0; i < 8; ++i)
                #pragma unroll
                for (int j = 0; j < 8; ++j)
                    acc[i][j] = fmaf(av[i], bv[j], acc[i][j]);
        }
        __syncthreads();
    }

    float biasv[8], lwv[8];
    #pragma unroll
    for (int j = 0; j < 8; ++j) {
        int n  = n0 + ty * 8 + j;
        int nc = (n < NOUT) ? n : 0;
        int pm = (nc / 5) * 6 + (nc % 5);
        biasv[j] = bias[pm];
        lwv[j]   = logsigf(wildc[nc]);
    }
    #pragma unroll
    for (int i = 0; i < 8; ++i) {
        int v = v0 + ((i < 4) ? (tx * 4 + i) : (64 + tx * 4 + (i - 4)));
        if (v >= V_) continue;
        float r[8];
        #pragma unroll
        for (int j = 0; j < 8; ++j)
            r[j] = fmaxf(logsigf(acc[i][j] + biasv[j]), lwv[j]);
        float* dst = cw + (size_t)v * CWS + n0 + ty * 8;
        if (n0 + ty * 8     < NOUT) *(float4*)dst       = make_float4(r[0], r[1], r[2], r[3]);
        if (n0 + ty * 8 + 4 < NOUT) *(float4*)(dst + 4) = make_float4(r[4], r[5], r[6], r[7]);
    }
}

// ---------------- scan (pipelined LDS staging) + finalize ----------------

// 3-buffer, depth-2 pipeline with counted s_waitcnt vmcnt(3) + raw s_barrier
// (one barrier per round). Bit-identical values.
__global__ __launch_bounds__(192) void k2_scan(
    const int* __restrict__ docs,
    const int* __restrict__ doc_lens,
    const float* __restrict__ cw,
    float* __restrict__ cs)
{
    const int ci = blockIdx.x;
    const int b  = blockIdx.y;
    const int t0 = ci * TCHUNK;
    const int ts = (t0 >= WARM) ? (t0 - WARM) : 0;
    const int dl = doc_lens[b];
    const int te = min(t0 + TCHUNK, dl);
    const int nt = te - ts;              // tokens to process (may be <= 0)

    __shared__ int   toks[TCHUNK + WARM];
    __shared__ float rows[KVBUF][3][768];   // 27 KB: [buf][row-in-round][752 used]

    const int t    = threadIdx.x;
    const int lane = t & 63;
    const int w    = t >> 6;             // wave 0..2

    if (t < TCHUNK + WARM) {
        int tt = ts + t;
        toks[t] = docs[b * L_ + min(tt, L_ - 1)];
    }
    __syncthreads();                     // toks ready; drains all prior vmem

    const int p      = t;                // pattern if < P_
    const int e      = (p < 50) ? 3 : (p < 100) ? 4 : 5;
    const int warm_n = t0 - ts;
    float h1 = NEGF, h2 = NEGF, h3 = NEGF, h4 = NEGF, h5 = NEGF, sc = NEGF;

    const int nrounds = (nt > 0) ? (nt + 2) / 3 : 0;

    // prologue: issue DMA for rounds 0 and 1 (wave w stages row w of a round)
    for (int r0 = 0; r0 < 2; ++r0) {
        if (r0 >= nrounds) break;
        int idx = min(3 * r0 + w, nt - 1);
        const char* rowp = (const char*)(cw + (size_t)toks[idx] * CWS);
        char* lbase = (char*)&rows[r0][w][0];
        #pragma unroll
        for (int jj = 0; jj < 3; ++jj)
            gload_lds16(rowp + jj * 1024 + lane * 16,
                        lbase + jj * 1024 + lane * 16);
    }

    int bufc = 0;
    for (int r = 0; r < nrounds; ++r) {
        // drain THIS round's DMA only; keep round r+1's 3 loads in flight
        if (r + 1 < nrounds) {
            asm volatile("s_waitcnt vmcnt(3)" ::: "memory");
        } else {
            asm volatile("s_waitcnt vmcnt(0)" ::: "memory");
        }
        __builtin_amdgcn_s_barrier();
        asm volatile("" ::: "memory");   // fence: no rows-read hoists above barrier

        if (r + 2 < nrounds) {           // prefetch round r+2 (buffer of round r-1)
            int rn  = r + 2;
            int idx = min(3 * rn + w, nt - 1);
            const char* rowp = (const char*)(cw + (size_t)toks[idx] * CWS);
            int bn = bufc + 2; if (bn >= KVBUF) bn -= KVBUF;
            char* lbase = (char*)&rows[bn][w][0];
            #pragma unroll
            for (int jj = 0; jj < 3; ++jj)
                gload_lds16(rowp + jj * 1024 + lane * 16,
                            lbase + jj * 1024 + lane * 16);
        }

        #pragma unroll
        for (int u = 0; u < 3; ++u) {
            int i2 = 3 * r + u;
            if (i2 >= nt) break;
            if (p < P_) {
                const float* rp = &rows[bufc][u][p * 5];
                float c0 = rp[0], c1 = rp[1], c2 = rp[2], c3 = rp[3], c4 = rp[4];
                h5 = h4 + c4;
                h4 = h3 + c3;
                h3 = h2 + c2;
                h2 = h1 + c1;
                h1 = c0;                 // h0 = 0 always
                if (i2 >= warm_n) {
                    float esv = (e == 3) ? h3 : (e == 4) ? h4 : h5;
                    sc = fmaxf(sc, esv);
                }
            }
        }
        bufc = (bufc + 1 == KVBUF) ? 0 : bufc + 1;
        // no second barrier: the barrier at top of round r+1 orders
        // compute(r) (all waves) before DMA(r+3) overwrites buf[r%3]
    }
    if (p < P_) cs[(size_t)(b * NCHUNK + ci) * CS_STRIDE + p] = sc;
}

__device__ __forceinline__ float block_sum192(float v, volatile float* red, int tid) {
    #pragma unroll
    for (int off = 32; off > 0; off >>= 1) v += __shfl_down(v, off, 64);
    __syncthreads();
    if ((tid & 63) == 0) red[tid >> 6] = v;
    __syncthreads();
    return red[0] + red[1] + red[2];
}

__global__ __launch_bounds__(192) void k3_final(
    const float* __restrict__ cs,
    const float* __restrict__ gamma,
    const float* __restrict__ beta,
    const float* __restrict__ lw,
    const float* __restrict__ lb,
    float* __restrict__ out)
{
    __shared__ float red[3];
    const int b   = blockIdx.x;
    const int tid = threadIdx.x;
    float s = 0.f;
    if (tid < P_) {
        float m = NEGF;
        const float* row = cs + (size_t)b * NCHUNK * CS_STRIDE + tid;
        #pragma unroll
        for (int ci = 0; ci < NCHUNK; ++ci) m = fmaxf(m, row[ci * CS_STRIDE]);
        s = expf(m);
    }
    float mu = block_sum192(s, red, tid) * (1.f / P_);
    float d  = (tid < P_) ? (s - mu) : 0.f;
    float var = block_sum192(d * d, red, tid) * (1.f / P_);
    float bin = 0.f;
    if (tid < P_) {
        float norm = (s - mu) * rsqrtf(var + 1e-5f) * gamma[tid] + beta[tid];
        bin = (norm > 0.f) ? 1.f : 0.f;
    }
    float o0 = block_sum192((tid < P_) ? bin * lw[tid]      : 0.f, red, tid);
    float o1 = block_sum192((tid < P_) ? bin * lw[P_ + tid] : 0.f, red, tid);
    if (tid == 0) {
        out[b * 2 + 0] = o0 + lb[0];
        out[b * 2 + 1] = o1 + lb[1];
    }
}

extern "C" void kernel_launch(void* const* d_in, const int* in_sizes, int n_in,
                              void* d_out, int out_size, void* d_ws, size_t ws_size,
                              hipStream_t stream)
{
    const int*   docs  = (const int*)  d_in[0];
    const int*   dlens = (const int*)  d_in[1];
    const float* emb   = (const float*)d_in[2];
    const float* diags = (const float*)d_in[3];
    const float* bias  = (const float*)d_in[4];
    const float* wildc = (const float*)d_in[5];
    const float* gamma = (const float*)d_in[6];
    const float* beta  = (const float*)d_in[7];
    const float* lw    = (const float*)d_in[8];
    const float* lb    = (const float*)d_in[9];
    float* out = (float*)d_out;

    // ws layout: cw | cs | a_t | b_t
    const size_t cw_b = (size_t)V_ * CWS * 4;                 // 60,160,000
    const size_t cs_b = (size_t)B_ * NCHUNK * CS_STRIDE * 4;  // 655,360
    const size_t at_b = (size_t)NVG * NIT * TILE_U4 * 16;     // 25,722,880
    const size_t bt_b = (size_t)NJ  * NIT * TILE_U4 * 16;     // 983,040
    const size_t need = cw_b + cs_b + at_b + bt_b;

    char* base = (char*)d_ws;
    float* cw = (float*)base;
    float* cs = (float*)(base + cw_b);
    uint4* at = (uint4*)(base + cw_b + cs_b);
    uint4* bt = (uint4*)(base + cw_b + cs_b + at_b);

    if (ws_size >= need) {
        p12_split<<<NVG * 5 + NJ * NIT, 256, 0, stream>>>(emb, diags, at, bt);
        // 240 blocks: 80 group-pair chunks x 3 n-blocks, XCD-colocated siblings
        k1m_gemm<<<240, 512, 0, stream>>>(at, bt, bias, wildc, cw);
    } else {
        dim3 g1((V_ + BM - 1) / BM, (NOUT + BN - 1) / BN);
        k1_gemm_cw<<<g1, 256, 0, stream>>>(emb, diags, bias, wildc, cw);
    }

    dim3 g2(NCHUNK, B_);
    k2_scan<<<g2, 192, 0, stream>>>(docs, dlens, cw, cs);
    k3_final<<<B_, 192, 0, stream>>>(cs, gamma, beta, lw, lb, out);
}